// Round 13
// baseline (282.586 us; speedup 1.0000x reference)
//
#include <hip/hip_runtime.h>
#include <hip/hip_bf16.h>
#include <cstdint>
#include <cstddef>

#define ALPHA_ 0.1f

static inline int cdiv(int a, int b) { return (a + b - 1) / b; }

typedef __attribute__((ext_vector_type(8))) short short8;
typedef __attribute__((ext_vector_type(4))) short short4v;
typedef __attribute__((ext_vector_type(4))) float float4v;

struct P12 { float* p[12]; };

__device__ __forceinline__ void gload_lds16(const void* g, void* l) {
  __builtin_amdgcn_global_load_lds((const __attribute__((address_space(1))) unsigned int*)g,
                                   (__attribute__((address_space(3))) unsigned int*)l,
                                   16, 0, 0);
}

// ---------------- WtT builder: per-32k-tile [kg][col][e] bf16 layout of W (K x 128) -------
__global__ __launch_bounds__(256) void make_wtT(const float* __restrict__ W,
                                                __hip_bfloat16* __restrict__ WtT,
                                                int K)
{
  __shared__ float tile[32][129];
  const int t  = threadIdx.x;
  const int s  = blockIdx.x;
  const int k0 = s * 32;
#pragma unroll
  for (int pass = 0; pass < 4; ++pass) {
    int idx = pass * 1024 + t * 4;
    int k = idx >> 7, c = idx & 127;
    float4v v;
    const float* src = W + (size_t)(k0 + k) * 128 + c;
    if (k0 + k < K) v = *(const float4v*)src;
    else            v = (float4v){0.f, 0.f, 0.f, 0.f};
    tile[k][c] = v.x; tile[k][c + 1] = v.y; tile[k][c + 2] = v.z; tile[k][c + 3] = v.w;
  }
  __syncthreads();
#pragma unroll
  for (int pass = 0; pass < 16; ++pass) {
    int idx = pass * 256 + t;
    int kg = idx >> 10, rem = idx & 1023;
    int c = rem >> 3, e = rem & 7;
    WtT[(size_t)s * 4096 + idx] = __float2bfloat16(tile[kg * 8 + e][c]);
  }
}

// ---------------- init GEMM (frozen R12: BM=256, BK=64, 2-phase, 48KB LDS) ----------------
template<int KSPLIT>
__global__ __launch_bounds__(512, 4) void init_mfma6(
    const float* __restrict__ Am, const __hip_bfloat16* __restrict__ Wtm, int Nm_, int nbm, int Kpm,
    const float* __restrict__ Ad, const __hip_bfloat16* __restrict__ Wtd, int Nd_, int Kpd,
    P12 parr)
{
  __shared__ __align__(16) __hip_bfloat16 lds_a[256 * 64];   // 32KB
  __shared__ __align__(16) __hip_bfloat16 lds_w[2 * 4096];   // 16KB

  const int t    = threadIdx.x;
  const int lane = t & 63;
  const int wv   = t >> 6;

  const int chunk = blockIdx.x % KSPLIT;
  int mb          = blockIdx.x / KSPLIT;

  const float* A; const __hip_bfloat16* Wt; int N, K, Kpad, rowoff, rb;
  if (mb < nbm) { A = Am; Wt = Wtm; N = Nm_; K = Nm_; Kpad = Kpm; rowoff = 0;   rb = mb; }
  else          { A = Ad; Wt = Wtd; N = Nd_; K = Nd_; Kpad = Kpd; rowoff = Nm_; rb = mb - nbm; }

  float* Cp = parr.p[chunk];

  const int St = Kpad / 64;
  const int s0 = (int)(((long)St * chunk) / KSPLIT);
  const int s1 = (int)(((long)St * (chunk + 1)) / KSPLIT);

  const int row_g0 = rb * 256;

  const float* apass[8];
  int aw_byte[8];
#pragma unroll
  for (int p = 0; p < 8; ++p) {
    int f   = p * 512 + t;
    int row = f >> 4, kq = f & 15;
    int rg  = row_g0 + row; if (rg > N - 1) rg = N - 1;
    apass[p] = A + (size_t)rg * K + kq * 4;
    int c = kq >> 1, h = kq & 1;
    aw_byte[p] = row * 128 + ((c ^ (row & 7)) << 4) + h * 8;
  }

  const int rloc = lane & 15;
  const int kg   = lane >> 4;
  int a_rbyte[2][2];
#pragma unroll
  for (int g = 0; g < 2; ++g) {
    int row_l = wv * 32 + g * 16 + rloc;
#pragma unroll
    for (int sub = 0; sub < 2; ++sub) {
      int c = sub * 4 + kg;
      a_rbyte[g][sub] = row_l * 128 + ((c ^ (row_l & 7)) << 4);
    }
  }
  int w_roff[8];
#pragma unroll
  for (int mt = 0; mt < 8; ++mt)
    w_roff[mt] = (mt * 16 + rloc) * 8;

  float4v accA[8], accB[8];
#pragma unroll
  for (int mt = 0; mt < 8; ++mt) { accA[mt] = (float4v){0,0,0,0}; accB[mt] = (float4v){0,0,0,0}; }

  const char* wt_bytes = (const char*)Wt;
  const size_t amax = (size_t)N * K - 4;

  for (int s = s0; s < s1; ++s) {
#pragma unroll
    for (int i = 0; i < 2; ++i) {
      gload_lds16(wt_bytes + (size_t)(s * 2 + i) * 8192 + (size_t)t * 16,
                  (char*)lds_w + (size_t)i * 8192 + (size_t)(wv * 64) * 16);
    }
    float4v av[8];
    const int kb = s * 64;
#pragma unroll
    for (int p = 0; p < 8; ++p) {
      const float* src = apass[p] + kb;
      ptrdiff_t rel = src - A;
      av[p] = *(const float4v*)(A + (((size_t)rel > amax) ? amax : (size_t)rel));
    }
#pragma unroll
    for (int p = 0; p < 8; ++p) {
      union { short4v v; __hip_bfloat16 h[4]; } pk;
      pk.h[0] = __float2bfloat16(av[p].x); pk.h[1] = __float2bfloat16(av[p].y);
      pk.h[2] = __float2bfloat16(av[p].z); pk.h[3] = __float2bfloat16(av[p].w);
      *(short4v*)((char*)lds_a + aw_byte[p]) = pk.v;
    }
    __syncthreads();

#pragma unroll
    for (int sub = 0; sub < 2; ++sub) {
      short8 afA = *(const short8*)((const char*)lds_a + a_rbyte[0][sub]);
      short8 afB = *(const short8*)((const char*)lds_a + a_rbyte[1][sub]);
      const __hip_bfloat16* lw = lds_w + sub * 4096 + kg * 1024;
#pragma unroll
      for (int mt = 0; mt < 8; ++mt) {
        short8 wfrag = *(const short8*)(lw + w_roff[mt]);
        accA[mt] = __builtin_amdgcn_mfma_f32_16x16x32_bf16(wfrag, afA, accA[mt], 0, 0, 0);
        accB[mt] = __builtin_amdgcn_mfma_f32_16x16x32_bf16(wfrag, afB, accB[mt], 0, 0, 0);
      }
    }
    __syncthreads();
  }

#pragma unroll
  for (int g = 0; g < 2; ++g) {
    int row = row_g0 + wv * 32 + g * 16 + rloc;
    if (row < N) {
      float* dst = Cp + (size_t)(rowoff + row) * 128 + kg * 4;
#pragma unroll
      for (int mt = 0; mt < 8; ++mt)
        *(float4v*)(dst + mt * 16) = (g == 0) ? accA[mt] : accB[mt];
    }
  }
}

// sum NP f32 partials -> initb (bf16) + both sections of state (bf16)
template<int NP>
__global__ __launch_bounds__(256) void combineN(
    P12 parr, __hip_bfloat16* __restrict__ initb, __hip_bfloat16* __restrict__ state,
    int n4, int NtD)
{
  int i = blockIdx.x * 256 + threadIdx.x;
  if (i >= n4) return;
  float4v s = ((const float4v*)parr.p[0])[i];
#pragma unroll
  for (int j = 1; j < NP; ++j) {
    float4v x = ((const float4v*)parr.p[j])[i];
    s.x += x.x; s.y += x.y; s.z += x.z; s.w += x.w;
  }
  union { short4v v; __hip_bfloat16 h[4]; } b;
  b.h[0] = __float2bfloat16(s.x); b.h[1] = __float2bfloat16(s.y);
  b.h[2] = __float2bfloat16(s.z); b.h[3] = __float2bfloat16(s.w);
  *(short4v*)(initb + (size_t)i * 4) = b.v;
  *(short4v*)(state + (size_t)i * 4) = b.v;
  *(short4v*)(state + (size_t)NtD + (size_t)i * 4) = b.v;
}

// ---------------- gather core ----------------
template<int L, int PP>
__device__ __forceinline__ float gath(const __hip_bfloat16* __restrict__ sect,
                                      const int* __restrict__ paths,
                                      const float* __restrict__ pw, int n, int N, int d)
{
  float pwv[L];
#pragma unroll
  for (int l = 0; l < L; ++l) pwv[l] = pw[l * 128 + d];
  float acc = 0.f;
  const int* ip0 = paths + (size_t)n * L;
#pragma unroll
  for (int p = 0; p < PP; ++p) {
    const int* ip = ip0 + (size_t)p * N * L;
    int idx[L];
#pragma unroll
    for (int l = 0; l < L; ++l) idx[l] = ip[l];
#pragma unroll
    for (int l = 0; l < L; ++l)
      acc = fmaf(pwv[l], __bfloat162float(sect[(size_t)idx[l] * 128 + d]), acc);
  }
  return acc;
}

// ---------------- FUSED layer: gather 16 nodes -> LDS, then fc + residual ----------------
template<int LMM, int LMD, int PP>
__global__ __launch_bounds__(256) void layer_fused(
    const __hip_bfloat16* __restrict__ stateIn,
    const int* __restrict__ paths_mm, const int* __restrict__ paths_dd, const int* __restrict__ paths_md,
    const float* __restrict__ pw1l, const float* __restrict__ pw2l,
    const float* __restrict__ fcWl, const __hip_bfloat16* __restrict__ initb,
    __hip_bfloat16* __restrict__ stateOut,
    int Nm, int Nd, int nbm, int nbd)
{
  __shared__ float r_lds[16][128];
  const int t  = threadIdx.x;
  const int Nt = Nm + Nd;
  int b = blockIdx.x;

  const __hip_bfloat16* sect; const int* paths; const float* pw;
  int N, rowbase, nb; bool md;
  if (b < nbm)            { sect = stateIn;                     paths = paths_mm; pw = pw1l; N = Nm; rowbase = 0;  nb = b;             md = false; }
  else if (b < nbm + nbd) { sect = stateIn + (size_t)Nm * 128;  paths = paths_dd; pw = pw1l; N = Nd; rowbase = Nm; nb = b - nbm;       md = false; }
  else                    { sect = stateIn + (size_t)Nt * 128;  paths = paths_md; pw = pw2l; N = Nt; rowbase = Nt; nb = b - nbm - nbd; md = true;  }

  const int d   = t & 127;
  const int sub = t >> 7;
  const int n0  = nb * 16;

#pragma unroll
  for (int i = 0; i < 8; ++i) {
    int slot = sub + 2 * i;
    int n = n0 + slot;
    int ng = (n < N) ? n : (N - 1);
    float acc = md ? gath<LMD, PP>(sect, paths, pw, ng, N, d)
                   : gath<LMM, PP>(sect, paths, pw, ng, N, d);
    r_lds[slot][d] = acc * (1.0f / (float)PP);
  }
  __syncthreads();

  const int col = d;
  const int rh  = sub;
  float acc2[8];
#pragma unroll
  for (int j = 0; j < 8; ++j) acc2[j] = 0.f;
#pragma unroll 4
  for (int k = 0; k < 128; k += 8) {
    float w[8];
#pragma unroll
    for (int kk = 0; kk < 8; ++kk) w[kk] = fcWl[(size_t)(k + kk) * 128 + col];
#pragma unroll
    for (int j = 0; j < 8; ++j) {
      const float* rp = &r_lds[rh * 8 + j][k];
#pragma unroll
      for (int kk = 0; kk < 8; ++kk) acc2[j] = fmaf(rp[kk], w[kk], acc2[j]);
    }
  }
#pragma unroll
  for (int j = 0; j < 8; ++j) {
    int n = n0 + rh * 8 + j;
    if (n < N) {
      int rr = rowbase + n;
      int rbase = (rr < Nt) ? rr : rr - Nt;
      float v = ALPHA_ * __bfloat162float(initb[(size_t)rbase * 128 + col])
              + (1.f - ALPHA_) * fmaxf(acc2[j], 0.f);
      stateOut[(size_t)rr * 128 + col] = __float2bfloat16(v);
    }
  }
}

// ---------------- unfused fallbacks ----------------
__global__ __launch_bounds__(256) void gather_einsum_rt(
    const __hip_bfloat16* __restrict__ feats, const int* __restrict__ paths,
    const float* __restrict__ pw, float* __restrict__ r, int N, int P, int L)
{
  const int d = threadIdx.x & 127;
  const int n = blockIdx.x * 2 + (threadIdx.x >> 7);
  if (n >= N) return;
  float acc = 0.f;
  for (int p = 0; p < P; ++p) {
    const int* ip = paths + ((size_t)p * N + n) * L;
    for (int l = 0; l < L; ++l)
      acc = fmaf(pw[l * 128 + d], __bfloat162float(feats[(size_t)ip[l] * 128 + d]), acc);
  }
  r[(size_t)n * 128 + d] = acc * (1.0f / (float)P);
}

template<int TR>
__global__ __launch_bounds__(256) void fc_all(
    const float* __restrict__ Rm, const float* __restrict__ W,
    const __hip_bfloat16* __restrict__ initb, __hip_bfloat16* __restrict__ state, int Ntot, int Nt)
{
  const int col = threadIdx.x & 127;
  const int rh  = __builtin_amdgcn_readfirstlane((int)(threadIdx.x >> 7));
  const int row0 = blockIdx.x * (2 * TR) + rh * TR;
  const float* arow[TR];
#pragma unroll
  for (int r = 0; r < TR; ++r) {
    int rr = row0 + r; if (rr > Ntot - 1) rr = Ntot - 1;
    arow[r] = Rm + (size_t)rr * 128;
  }
  float acc[TR];
#pragma unroll
  for (int r = 0; r < TR; ++r) acc[r] = 0.f;
#pragma unroll 4
  for (int k = 0; k < 128; k += 8) {
    float w[8];
#pragma unroll
    for (int kk = 0; kk < 8; ++kk) w[kk] = W[(size_t)(k + kk) * 128 + col];
#pragma unroll
    for (int r = 0; r < TR; ++r) {
      const float* ap = arow[r] + k;
#pragma unroll
      for (int kk = 0; kk < 8; ++kk) acc[r] = fmaf(ap[kk], w[kk], acc[r]);
    }
  }
#pragma unroll
  for (int r = 0; r < TR; ++r) {
    int rr = row0 + r;
    if (rr < Ntot) {
      int rbase = (rr < Nt) ? rr : rr - Nt;
      float v = ALPHA_ * __bfloat162float(initb[(size_t)rbase * 128 + col])
              + (1.f - ALPHA_) * fmaxf(acc[r], 0.f);
      state[(size_t)rr * 128 + col] = __float2bfloat16(v);
    }
  }
}

// ---------------- MLP collapse, fully fused (H1 == 64) ----------------
// block = one row of w01; 64 threads each own one column c; then dot with W2 via wave-reduce.
__global__ __launch_bounds__(64) void collapse12(
    const float* __restrict__ W0, const float* __restrict__ b0,
    const float* __restrict__ W1, const float* __restrict__ b1,
    const float* __restrict__ W2, const float* __restrict__ b2,
    float* __restrict__ w512, float* __restrict__ csc, int E, int K0, int H1)
{
  const int row = blockIdx.x;
  const int c   = threadIdx.x;
  const float* src = (row < E) ? W0 + (size_t)row * K0 : b0;
  float base = (row < E) ? 0.f : b1[c];
  float a0 = 0.f, a1 = 0.f, a2 = 0.f, a3 = 0.f;
#pragma unroll 4
  for (int k = 0; k < K0; k += 4) {
    a0 = fmaf(src[k + 0], W1[(size_t)(k + 0) * H1 + c], a0);
    a1 = fmaf(src[k + 1], W1[(size_t)(k + 1) * H1 + c], a1);
    a2 = fmaf(src[k + 2], W1[(size_t)(k + 2) * H1 + c], a2);
    a3 = fmaf(src[k + 3], W1[(size_t)(k + 3) * H1 + c], a3);
  }
  float s = (base + ((a0 + a1) + (a2 + a3))) * W2[c];
#pragma unroll
  for (int off = 32; off > 0; off >>= 1) s += __shfl_down(s, off);
  if (c == 0) {
    if (row < E) w512[row] = s;
    else         csc[0]    = s + b2[0];
  }
}

// legacy two-stage collapse (fallback for H1 != 64)
__global__ void collapse1(const float* __restrict__ W0, const float* __restrict__ b0,
                          const float* __restrict__ W1, const float* __restrict__ b1,
                          float* __restrict__ w01, float* __restrict__ b01,
                          int E, int K0, int H1)
{
  int row = blockIdx.x; int c = threadIdx.x;
  if (c >= H1) return;
  const float* src; float base;
  if (row < E) { src = W0 + (size_t)row * K0; base = 0.f; }
  else         { src = b0; base = b1[c]; }
  float acc = base;
  for (int k = 0; k < K0; ++k) acc = fmaf(src[k], W1[(size_t)k * H1 + c], acc);
  if (row < E) w01[(size_t)row * H1 + c] = acc; else b01[c] = acc;
}

__global__ void collapse2(const float* __restrict__ w01, const float* __restrict__ b01,
                          const float* __restrict__ W2, const float* __restrict__ b2,
                          float* __restrict__ w512, float* __restrict__ csc,
                          int E, int H1)
{
  int i = blockIdx.x * blockDim.x + threadIdx.x;
  if (i < E) {
    float a = 0.f;
    for (int j = 0; j < H1; ++j) a = fmaf(w01[(size_t)i * H1 + j], W2[j], a);
    w512[i] = a;
  } else if (i == E) {
    float a = b2[0];
    for (int j = 0; j < H1; ++j) a = fmaf(b01[j], W2[j], a);
    csc[0] = a;
  }
}

__global__ __launch_bounds__(256) void node_partial(
    const __hip_bfloat16* __restrict__ Fmm, const __hip_bfloat16* __restrict__ Fdd,
    const __hip_bfloat16* __restrict__ Fmd,
    const float* __restrict__ w512, float* __restrict__ uv, int Nm, int Nt)
{
  int gid = blockIdx.x * blockDim.x + threadIdx.x;
  int wid = gid >> 6;
  int lane = threadIdx.x & 63;
  if (wid >= Nt) return;
  bool isM = wid < Nm;
  const __hip_bfloat16* X = isM ? (Fmm + (size_t)wid * 128) : (Fdd + (size_t)(wid - Nm) * 128);
  const __hip_bfloat16* Y = Fmd + (size_t)wid * 128;
  const float* w1 = w512 + (isM ? 0 : 256);
  const float* w2 = w1 + 128;
  float s = __bfloat162float(X[lane]) * w1[lane];
  s = fmaf(__bfloat162float(X[lane + 64]), w1[lane + 64], s);
  s = fmaf(__bfloat162float(Y[lane]), w2[lane], s);
  s = fmaf(__bfloat162float(Y[lane + 64]), w2[lane + 64], s);
#pragma unroll
  for (int off = 32; off > 0; off >>= 1) s += __shfl_down(s, off);
  if (lane == 0) uv[wid] = s;
}

__global__ __launch_bounds__(256) void score_kernel(
    const int* __restrict__ samples, const float* __restrict__ u, const float* __restrict__ v,
    const float* __restrict__ csc, float* __restrict__ out, int S)
{
  int s = blockIdx.x * blockDim.x + threadIdx.x;
  if (s >= S) return;
  const int2 ij = ((const int2*)samples)[s];
  float x = u[ij.x] + v[ij.y] + csc[0];
  out[s] = 1.0f / (1.0f + expf(-x));
}

extern "C" void kernel_launch(void* const* d_in, const int* in_sizes, int n_in,
                              void* d_out, int out_size, void* d_ws, size_t ws_size,
                              hipStream_t stream)
{
  const int*   paths_mm = (const int*)d_in[0];
  const int*   paths_dd = (const int*)d_in[1];
  const int*   paths_md = (const int*)d_in[2];
  const float* miRNA    = (const float*)d_in[3];
  const float* disease  = (const float*)d_in[4];
  const int*   samples  = (const int*)d_in[5];
  const float* Wm  = (const float*)d_in[6];
  const float* Wd  = (const float*)d_in[7];
  const float* pw1 = (const float*)d_in[8];
  const float* pw2 = (const float*)d_in[9];
  const float* fcW = (const float*)d_in[10];
  const float* W0  = (const float*)d_in[11];
  const float* b0  = (const float*)d_in[12];
  const float* W1  = (const float*)d_in[13];
  const float* b1  = (const float*)d_in[14];
  const float* W2  = (const float*)d_in[15];
  const float* b2  = (const float*)d_in[16];

  const int D  = 128;
  const int Nm = in_sizes[6] / D;
  const int Nd = in_sizes[7] / D;
  const int Nt = Nm + Nd;
  const int S  = in_sizes[5] / 2;
  const int layers = in_sizes[10] / (D * D);
  const int L1 = in_sizes[8] / (layers * D);
  const int L2 = in_sizes[9] / (layers * D);
  const int P  = in_sizes[0] / (Nm * L1);
  const int E  = 4 * D;
  const int K0 = in_sizes[12];
  const int H1 = in_sizes[14];
  const int Kpm = cdiv(Nm, 64) * 64;   // 8000
  const int Kpd = cdiv(Nd, 64) * 64;   // 6016
  const size_t NtD = (size_t)Nt * D;

  float* out = (float*)d_out;
  float* ws  = (float*)d_ws;
  size_t off = 0;
  __hip_bfloat16* initb  = (__hip_bfloat16*)(ws + off); off += NtD / 2;   // bf16 residual base
  __hip_bfloat16* stateA = (__hip_bfloat16*)(ws + off); off += NtD;       // 2*NtD bf16
  __hip_bfloat16* stateB = (__hip_bfloat16*)(ws + off); off += NtD;       // 2*NtD bf16
  float* w01    = ws + off; off += (size_t)E * H1;
  float* b01    = ws + off; off += H1;
  float* w512   = ws + off; off += E;
  float* csc    = ws + off; off += 1;
  float* uv     = ws + off; off += Nt;
  __hip_bfloat16* WtTm = (__hip_bfloat16*)(ws + off); off += (size_t)D * Kpm / 2;
  __hip_bfloat16* WtTd = (__hip_bfloat16*)(ws + off); off += (size_t)D * Kpd / 2;
  float* pextra = ws + off;
  (void)n_in; (void)out_size;

  // 1. tile-major bf16 weight transposes
  make_wtT<<<Kpm / 32, 256, 0, stream>>>(Wm, WtTm, Nm);
  make_wtT<<<Kpd / 32, 256, 0, stream>>>(Wd, WtTd, Nd);

  // 2. MLP collapse (fused single kernel when H1 == wave size)
  if (H1 == 64) {
    collapse12<<<E + 1, 64, 0, stream>>>(W0, b0, W1, b1, W2, b2, w512, csc, E, K0, H1);
  } else {
    collapse1<<<E + 1, H1 <= 1024 ? H1 : 1024, 0, stream>>>(W0, b0, W1, b1, w01, b01, E, K0, H1);
    collapse2<<<cdiv(E + 1, 256), 256, 0, stream>>>(w01, b01, W2, b2, w512, csc, E, H1);
  }

  // 3. init GEMMs (frozen R12): BM=256 / BK=64, split-K sized to workspace
  {
    int nbm = cdiv(Nm, 256), nbd = cdiv(Nd, 256);
    int n4 = (int)(NtD / 4);
    P12 parr;
    parr.p[0] = (float*)stateB;      // scratch until layer 0 (combineN runs before layers)
    for (int j = 0; j < 11; ++j) parr.p[1 + j] = pextra + (size_t)j * NtD;
    if ((off + 8 * NtD) * 4 <= ws_size) {
      init_mfma6<9><<<(nbm + nbd) * 9, 512, 0, stream>>>(
          miRNA, WtTm, Nm, nbm, Kpm, disease, WtTd, Nd, Kpd, parr);
      combineN<9><<<cdiv(n4, 256), 256, 0, stream>>>(parr, initb, stateA, n4, (int)NtD);
    } else if ((off + 5 * NtD) * 4 <= ws_size) {
      init_mfma6<6><<<(nbm + nbd) * 6, 512, 0, stream>>>(
          miRNA, WtTm, Nm, nbm, Kpm, disease, WtTd, Nd, Kpd, parr);
      combineN<6><<<cdiv(n4, 256), 256, 0, stream>>>(parr, initb, stateA, n4, (int)NtD);
    } else {
      init_mfma6<3><<<(nbm + nbd) * 3, 512, 0, stream>>>(
          miRNA, WtTm, Nm, nbm, Kpm, disease, WtTd, Nd, Kpd, parr);
      combineN<3><<<cdiv(n4, 256), 256, 0, stream>>>(parr, initb, stateA, n4, (int)NtD);
    }
  }

  // 4. path layers: fused gather+fc with ping-pong state
  const bool fuse_ok = (L1 == 4 && L2 == 6 && P == 8 &&
                        Nm % 16 == 0 && Nd % 16 == 0 && Nt % 16 == 0);
  __hip_bfloat16* cur = stateA;
  __hip_bfloat16* nxt = stateB;
  for (int l = 0; l < layers; ++l) {
    const float* pw1l = pw1 + (size_t)l * L1 * D;
    const float* pw2l = pw2 + (size_t)l * L2 * D;
    const float* fcWl = fcW + (size_t)l * D * D;
    if (fuse_ok) {
      int nbm16 = Nm / 16, nbd16 = Nd / 16, nbt16 = Nt / 16;
      layer_fused<4, 6, 8><<<nbm16 + nbd16 + nbt16, 256, 0, stream>>>(
          cur, paths_mm, paths_dd, paths_md, pw1l, pw2l, fcWl, initb, nxt,
          Nm, Nd, nbm16, nbd16);
    } else {
      float* bufR = pextra;
      gather_einsum_rt<<<cdiv(Nm, 2), 256, 0, stream>>>(cur, paths_mm, pw1l, bufR, Nm, P, L1);
      gather_einsum_rt<<<cdiv(Nd, 2), 256, 0, stream>>>(cur + (size_t)Nm * D, paths_dd, pw1l,
                                                        bufR + (size_t)Nm * D, Nd, P, L1);
      gather_einsum_rt<<<cdiv(Nt, 2), 256, 0, stream>>>(cur + NtD, paths_md, pw2l,
                                                        bufR + NtD, Nt, P, L2);
      fc_all<8><<<cdiv(2 * Nt, 16), 256, 0, stream>>>(
          bufR, fcWl, initb, nxt, 2 * Nt, Nt);
    }
    __hip_bfloat16* tmp = cur; cur = nxt; nxt = tmp;
  }

  // 5. per-node partial dots + scoring
  node_partial<<<cdiv(Nt * 64, 256), 256, 0, stream>>>(
      cur, cur + (size_t)Nm * D, cur + NtD, w512, uv, Nm, Nt);
  score_kernel<<<cdiv(S, 256), 256, 0, stream>>>(samples, uv, uv + Nm, csc, out, S);
}

// Round 14
// 270.346 us; speedup vs baseline: 1.0453x; 1.0453x over previous
//
#include <hip/hip_runtime.h>
#include <hip/hip_bf16.h>
#include <cstdint>
#include <cstddef>

#define ALPHA_ 0.1f

static inline int cdiv(int a, int b) { return (a + b - 1) / b; }

typedef __attribute__((ext_vector_type(8))) short short8;
typedef __attribute__((ext_vector_type(4))) short short4v;
typedef __attribute__((ext_vector_type(4))) float float4v;

struct P12 { float* p[12]; };

__device__ __forceinline__ void gload_lds16(const void* g, void* l) {
  __builtin_amdgcn_global_load_lds((const __attribute__((address_space(1))) unsigned int*)g,
                                   (__attribute__((address_space(3))) unsigned int*)l,
                                   16, 0, 0);
}

// ---------------- WtT builder: per-32k-tile [kg][col][e] bf16 layout of W (K x 128) -------
__global__ __launch_bounds__(256) void make_wtT(const float* __restrict__ W,
                                                __hip_bfloat16* __restrict__ WtT,
                                                int K)
{
  __shared__ float tile[32][129];
  const int t  = threadIdx.x;
  const int s  = blockIdx.x;
  const int k0 = s * 32;
#pragma unroll
  for (int pass = 0; pass < 4; ++pass) {
    int idx = pass * 1024 + t * 4;
    int k = idx >> 7, c = idx & 127;
    float4v v;
    const float* src = W + (size_t)(k0 + k) * 128 + c;
    if (k0 + k < K) v = *(const float4v*)src;
    else            v = (float4v){0.f, 0.f, 0.f, 0.f};
    tile[k][c] = v.x; tile[k][c + 1] = v.y; tile[k][c + 2] = v.z; tile[k][c + 3] = v.w;
  }
  __syncthreads();
#pragma unroll
  for (int pass = 0; pass < 16; ++pass) {
    int idx = pass * 256 + t;
    int kg = idx >> 10, rem = idx & 1023;
    int c = rem >> 3, e = rem & 7;
    WtT[(size_t)s * 4096 + idx] = __float2bfloat16(tile[kg * 8 + e][c]);
  }
}

// ---------------- init GEMM: BM=256, BK=64 (W traffic halved), 2-phase, 48KB LDS ----------
// 512 thr = 8 waves; wave wv owns rows wv*32..+32 (two 16-row groups) x all 128 cols.
// A: copy-like staging (1KB wave-runs) -> swizzled LDS [256][64]bf16 (XOR chunk with row&7).
// W: two 8KB 32k-tiles per step via linear glds from [kg][col][e] WtT.
template<int KSPLIT>
__global__ __launch_bounds__(512, 4) void init_mfma6(
    const float* __restrict__ Am, const __hip_bfloat16* __restrict__ Wtm, int Nm_, int nbm, int Kpm,
    const float* __restrict__ Ad, const __hip_bfloat16* __restrict__ Wtd, int Nd_, int Kpd,
    P12 parr)
{
  __shared__ __align__(16) __hip_bfloat16 lds_a[256 * 64];   // 32KB
  __shared__ __align__(16) __hip_bfloat16 lds_w[2 * 4096];   // 16KB

  const int t    = threadIdx.x;
  const int lane = t & 63;
  const int wv   = t >> 6;

  const int chunk = blockIdx.x % KSPLIT;
  int mb          = blockIdx.x / KSPLIT;

  const float* A; const __hip_bfloat16* Wt; int N, K, Kpad, rowoff, rb;
  if (mb < nbm) { A = Am; Wt = Wtm; N = Nm_; K = Nm_; Kpad = Kpm; rowoff = 0;   rb = mb; }
  else          { A = Ad; Wt = Wtd; N = Nd_; K = Nd_; Kpad = Kpd; rowoff = Nm_; rb = mb - nbm; }

  float* Cp = parr.p[chunk];

  const int St = Kpad / 64;
  const int s0 = (int)(((long)St * chunk) / KSPLIT);
  const int s1 = (int)(((long)St * (chunk + 1)) / KSPLIT);

  const int row_g0 = rb * 256;

  // ---- A staging map: pass p, flat f = p*512 + t (float4 units); row = f>>4, kq = f&15 ----
  const float* apass[8];
  int aw_byte[8];
#pragma unroll
  for (int p = 0; p < 8; ++p) {
    int f   = p * 512 + t;
    int row = f >> 4, kq = f & 15;
    int rg  = row_g0 + row; if (rg > N - 1) rg = N - 1;
    apass[p] = A + (size_t)rg * K + kq * 4;
    int c = kq >> 1, h = kq & 1;
    aw_byte[p] = row * 128 + ((c ^ (row & 7)) << 4) + h * 8;
  }

  // ---- compute-side frag offsets ----
  const int rloc = lane & 15;
  const int kg   = lane >> 4;
  int a_rbyte[2][2];   // [g][sub]
#pragma unroll
  for (int g = 0; g < 2; ++g) {
    int row_l = wv * 32 + g * 16 + rloc;
#pragma unroll
    for (int sub = 0; sub < 2; ++sub) {
      int c = sub * 4 + kg;
      a_rbyte[g][sub] = row_l * 128 + ((c ^ (row_l & 7)) << 4);
    }
  }
  int w_roff[8];
#pragma unroll
  for (int mt = 0; mt < 8; ++mt)
    w_roff[mt] = (mt * 16 + rloc) * 8;   // element offset within [kg] plane

  float4v accA[8], accB[8];              // g=0 / g=1 accumulators (static names)
#pragma unroll
  for (int mt = 0; mt < 8; ++mt) { accA[mt] = (float4v){0,0,0,0}; accB[mt] = (float4v){0,0,0,0}; }

  const char* wt_bytes = (const char*)Wt;
  const size_t amax = (size_t)N * K - 4;

  for (int s = s0; s < s1; ++s) {
    // ---- W: two 32k-tiles, one glds per thread per tile (linear src+dest) ----
#pragma unroll
    for (int i = 0; i < 2; ++i) {
      gload_lds16(wt_bytes + (size_t)(s * 2 + i) * 8192 + (size_t)t * 16,
                  (char*)lds_w + (size_t)i * 8192 + (size_t)(wv * 64) * 16);
    }
    // ---- A: 8 copy-like loads (1KB contiguous per wave-instr) ----
    float4v av[8];
    const int kb = s * 64;
#pragma unroll
    for (int p = 0; p < 8; ++p) {
      const float* src = apass[p] + kb;
      ptrdiff_t rel = src - A;
      av[p] = *(const float4v*)(A + (((size_t)rel > amax) ? amax : (size_t)rel));
    }
    // ---- cvt + swizzled LDS write (8B each) ----
#pragma unroll
    for (int p = 0; p < 8; ++p) {
      union { short4v v; __hip_bfloat16 h[4]; } pk;
      pk.h[0] = __float2bfloat16(av[p].x); pk.h[1] = __float2bfloat16(av[p].y);
      pk.h[2] = __float2bfloat16(av[p].z); pk.h[3] = __float2bfloat16(av[p].w);
      *(short4v*)((char*)lds_a + aw_byte[p]) = pk.v;
    }
    __syncthreads();

    // ---- compute: 2 subs x (2 afrag + 8 w-loads, 16 MFMA) ----
#pragma unroll
    for (int sub = 0; sub < 2; ++sub) {
      short8 afA = *(const short8*)((const char*)lds_a + a_rbyte[0][sub]);
      short8 afB = *(const short8*)((const char*)lds_a + a_rbyte[1][sub]);
      const __hip_bfloat16* lw = lds_w + sub * 4096 + kg * 1024;
#pragma unroll
      for (int mt = 0; mt < 8; ++mt) {
        short8 wfrag = *(const short8*)(lw + w_roff[mt]);
        accA[mt] = __builtin_amdgcn_mfma_f32_16x16x32_bf16(wfrag, afA, accA[mt], 0, 0, 0);
        accB[mt] = __builtin_amdgcn_mfma_f32_16x16x32_bf16(wfrag, afB, accB[mt], 0, 0, 0);
      }
    }
    __syncthreads();
  }

#pragma unroll
  for (int g = 0; g < 2; ++g) {
    int row = row_g0 + wv * 32 + g * 16 + rloc;
    if (row < N) {
      float* dst = Cp + (size_t)(rowoff + row) * 128 + kg * 4;
#pragma unroll
      for (int mt = 0; mt < 8; ++mt)
        *(float4v*)(dst + mt * 16) = (g == 0) ? accA[mt] : accB[mt];
    }
  }
}

// sum NP partials -> init (f32) + both sections of state (bf16)
template<int NP>
__global__ __launch_bounds__(256) void combineN(
    P12 parr, float4v* __restrict__ o_init, __hip_bfloat16* __restrict__ state,
    int n4, int NtD)
{
  int i = blockIdx.x * 256 + threadIdx.x;
  if (i >= n4) return;
  float4v s = ((const float4v*)parr.p[0])[i];
#pragma unroll
  for (int j = 1; j < NP; ++j) {
    float4v x = ((const float4v*)parr.p[j])[i];
    s.x += x.x; s.y += x.y; s.z += x.z; s.w += x.w;
  }
  o_init[i] = s;
  union { short4v v; __hip_bfloat16 h[4]; } b;
  b.h[0] = __float2bfloat16(s.x); b.h[1] = __float2bfloat16(s.y);
  b.h[2] = __float2bfloat16(s.z); b.h[3] = __float2bfloat16(s.w);
  *(short4v*)(state + (size_t)i * 4) = b.v;
  *(short4v*)(state + (size_t)NtD + (size_t)i * 4) = b.v;
}

// ---------------- gather core ----------------
template<int L, int PP>
__device__ __forceinline__ float gath(const __hip_bfloat16* __restrict__ sect,
                                      const int* __restrict__ paths,
                                      const float* __restrict__ pw, int n, int N, int d)
{
  float pwv[L];
#pragma unroll
  for (int l = 0; l < L; ++l) pwv[l] = pw[l * 128 + d];
  float acc = 0.f;
  const int* ip0 = paths + (size_t)n * L;
#pragma unroll
  for (int p = 0; p < PP; ++p) {
    const int* ip = ip0 + (size_t)p * N * L;
    int idx[L];
#pragma unroll
    for (int l = 0; l < L; ++l) idx[l] = ip[l];
#pragma unroll
    for (int l = 0; l < L; ++l)
      acc = fmaf(pwv[l], __bfloat162float(sect[(size_t)idx[l] * 128 + d]), acc);
  }
  return acc;
}

// ---------------- FUSED layer: gather 16 nodes -> LDS, then fc + residual ----------------
template<int LMM, int LMD, int PP>
__global__ __launch_bounds__(256) void layer_fused(
    const __hip_bfloat16* __restrict__ stateIn,
    const int* __restrict__ paths_mm, const int* __restrict__ paths_dd, const int* __restrict__ paths_md,
    const float* __restrict__ pw1l, const float* __restrict__ pw2l,
    const float* __restrict__ fcWl, const float* __restrict__ initb,
    __hip_bfloat16* __restrict__ stateOut,
    int Nm, int Nd, int nbm, int nbd)
{
  __shared__ float r_lds[16][128];
  const int t  = threadIdx.x;
  const int Nt = Nm + Nd;
  int b = blockIdx.x;

  const __hip_bfloat16* sect; const int* paths; const float* pw;
  int N, rowbase, nb; bool md;
  if (b < nbm)            { sect = stateIn;                     paths = paths_mm; pw = pw1l; N = Nm; rowbase = 0;  nb = b;             md = false; }
  else if (b < nbm + nbd) { sect = stateIn + (size_t)Nm * 128;  paths = paths_dd; pw = pw1l; N = Nd; rowbase = Nm; nb = b - nbm;       md = false; }
  else                    { sect = stateIn + (size_t)Nt * 128;  paths = paths_md; pw = pw2l; N = Nt; rowbase = Nt; nb = b - nbm - nbd; md = true;  }

  const int d   = t & 127;
  const int sub = t >> 7;
  const int n0  = nb * 16;

#pragma unroll
  for (int i = 0; i < 8; ++i) {
    int slot = sub + 2 * i;
    int n = n0 + slot;
    int ng = (n < N) ? n : (N - 1);
    float acc = md ? gath<LMD, PP>(sect, paths, pw, ng, N, d)
                   : gath<LMM, PP>(sect, paths, pw, ng, N, d);
    r_lds[slot][d] = acc * (1.0f / (float)PP);
  }
  __syncthreads();

  const int col = d;
  const int rh  = sub;
  float acc2[8];
#pragma unroll
  for (int j = 0; j < 8; ++j) acc2[j] = 0.f;
#pragma unroll 4
  for (int k = 0; k < 128; k += 8) {
    float w[8];
#pragma unroll
    for (int kk = 0; kk < 8; ++kk) w[kk] = fcWl[(size_t)(k + kk) * 128 + col];
#pragma unroll
    for (int j = 0; j < 8; ++j) {
      const float* rp = &r_lds[rh * 8 + j][k];
#pragma unroll
      for (int kk = 0; kk < 8; ++kk) acc2[j] = fmaf(rp[kk], w[kk], acc2[j]);
    }
  }
#pragma unroll
  for (int j = 0; j < 8; ++j) {
    int n = n0 + rh * 8 + j;
    if (n < N) {
      int rr = rowbase + n;
      int rbase = (rr < Nt) ? rr : rr - Nt;
      float v = ALPHA_ * initb[(size_t)rbase * 128 + col] + (1.f - ALPHA_) * fmaxf(acc2[j], 0.f);
      stateOut[(size_t)rr * 128 + col] = __float2bfloat16(v);
    }
  }
}

// ---------------- unfused fallbacks ----------------
__global__ __launch_bounds__(256) void gather_einsum_rt(
    const __hip_bfloat16* __restrict__ feats, const int* __restrict__ paths,
    const float* __restrict__ pw, float* __restrict__ r, int N, int P, int L)
{
  const int d = threadIdx.x & 127;
  const int n = blockIdx.x * 2 + (threadIdx.x >> 7);
  if (n >= N) return;
  float acc = 0.f;
  for (int p = 0; p < P; ++p) {
    const int* ip = paths + ((size_t)p * N + n) * L;
    for (int l = 0; l < L; ++l)
      acc = fmaf(pw[l * 128 + d], __bfloat162float(feats[(size_t)ip[l] * 128 + d]), acc);
  }
  r[(size_t)n * 128 + d] = acc * (1.0f / (float)P);
}

template<int TR>
__global__ __launch_bounds__(256) void fc_all(
    const float* __restrict__ Rm, const float* __restrict__ W,
    const float* __restrict__ initb, __hip_bfloat16* __restrict__ state, int Ntot, int Nt)
{
  const int col = threadIdx.x & 127;
  const int rh  = __builtin_amdgcn_readfirstlane((int)(threadIdx.x >> 7));
  const int row0 = blockIdx.x * (2 * TR) + rh * TR;
  const float* arow[TR];
#pragma unroll
  for (int r = 0; r < TR; ++r) {
    int rr = row0 + r; if (rr > Ntot - 1) rr = Ntot - 1;
    arow[r] = Rm + (size_t)rr * 128;
  }
  float acc[TR];
#pragma unroll
  for (int r = 0; r < TR; ++r) acc[r] = 0.f;
#pragma unroll 4
  for (int k = 0; k < 128; k += 8) {
    float w[8];
#pragma unroll
    for (int kk = 0; kk < 8; ++kk) w[kk] = W[(size_t)(k + kk) * 128 + col];
#pragma unroll
    for (int r = 0; r < TR; ++r) {
      const float* ap = arow[r] + k;
#pragma unroll
      for (int kk = 0; kk < 8; ++kk) acc[r] = fmaf(ap[kk], w[kk], acc[r]);
    }
  }
#pragma unroll
  for (int r = 0; r < TR; ++r) {
    int rr = row0 + r;
    if (rr < Ntot) {
      int rbase = (rr < Nt) ? rr : rr - Nt;
      float v = ALPHA_ * initb[(size_t)rbase * 128 + col] + (1.f - ALPHA_) * fmaxf(acc[r], 0.f);
      state[(size_t)rr * 128 + col] = __float2bfloat16(v);
    }
  }
}

// MLP collapse
__global__ void collapse1(const float* __restrict__ W0, const float* __restrict__ b0,
                          const float* __restrict__ W1, const float* __restrict__ b1,
                          float* __restrict__ w01, float* __restrict__ b01,
                          int E, int K0, int H1)
{
  int row = blockIdx.x; int c = threadIdx.x;
  if (c >= H1) return;
  const float* src; float base;
  if (row < E) { src = W0 + (size_t)row * K0; base = 0.f; }
  else         { src = b0; base = b1[c]; }
  float a0 = 0.f, a1 = 0.f, a2 = 0.f, a3 = 0.f;
#pragma unroll 4
  for (int k = 0; k < K0; k += 4) {
    a0 = fmaf(src[k + 0], W1[(size_t)(k + 0) * H1 + c], a0);
    a1 = fmaf(src[k + 1], W1[(size_t)(k + 1) * H1 + c], a1);
    a2 = fmaf(src[k + 2], W1[(size_t)(k + 2) * H1 + c], a2);
    a3 = fmaf(src[k + 3], W1[(size_t)(k + 3) * H1 + c], a3);
  }
  float acc = base + ((a0 + a1) + (a2 + a3));
  if (row < E) w01[(size_t)row * H1 + c] = acc; else b01[c] = acc;
}

__global__ void collapse2(const float* __restrict__ w01, const float* __restrict__ b01,
                          const float* __restrict__ W2, const float* __restrict__ b2,
                          float* __restrict__ w512, float* __restrict__ csc,
                          int E, int H1)
{
  int i = blockIdx.x * blockDim.x + threadIdx.x;
  if (i < E) {
    float a0 = 0.f, a1 = 0.f, a2 = 0.f, a3 = 0.f;
    for (int j = 0; j < H1; j += 4) {
      a0 = fmaf(w01[(size_t)i * H1 + j + 0], W2[j + 0], a0);
      a1 = fmaf(w01[(size_t)i * H1 + j + 1], W2[j + 1], a1);
      a2 = fmaf(w01[(size_t)i * H1 + j + 2], W2[j + 2], a2);
      a3 = fmaf(w01[(size_t)i * H1 + j + 3], W2[j + 3], a3);
    }
    w512[i] = (a0 + a1) + (a2 + a3);
  } else if (i == E) {
    float a = b2[0];
    for (int j = 0; j < H1; ++j) a = fmaf(b01[j], W2[j], a);
    csc[0] = a;
  }
}

__global__ __launch_bounds__(256) void node_partial(
    const __hip_bfloat16* __restrict__ Fmm, const __hip_bfloat16* __restrict__ Fdd,
    const __hip_bfloat16* __restrict__ Fmd,
    const float* __restrict__ w512, float* __restrict__ uv, int Nm, int Nt)
{
  int gid = blockIdx.x * blockDim.x + threadIdx.x;
  int wid = gid >> 6;
  int lane = threadIdx.x & 63;
  if (wid >= Nt) return;
  bool isM = wid < Nm;
  const __hip_bfloat16* X = isM ? (Fmm + (size_t)wid * 128) : (Fdd + (size_t)(wid - Nm) * 128);
  const __hip_bfloat16* Y = Fmd + (size_t)wid * 128;
  const float* w1 = w512 + (isM ? 0 : 256);
  const float* w2 = w1 + 128;
  float s = __bfloat162float(X[lane]) * w1[lane];
  s = fmaf(__bfloat162float(X[lane + 64]), w1[lane + 64], s);
  s = fmaf(__bfloat162float(Y[lane]), w2[lane], s);
  s = fmaf(__bfloat162float(Y[lane + 64]), w2[lane + 64], s);
#pragma unroll
  for (int off = 32; off > 0; off >>= 1) s += __shfl_down(s, off);
  if (lane == 0) uv[wid] = s;
}

__global__ __launch_bounds__(256) void score_kernel(
    const int* __restrict__ samples, const float* __restrict__ u, const float* __restrict__ v,
    const float* __restrict__ csc, float* __restrict__ out, int S)
{
  int s = blockIdx.x * blockDim.x + threadIdx.x;
  if (s >= S) return;
  const int2 ij = ((const int2*)samples)[s];
  float x = u[ij.x] + v[ij.y] + csc[0];
  out[s] = 1.0f / (1.0f + expf(-x));
}

extern "C" void kernel_launch(void* const* d_in, const int* in_sizes, int n_in,
                              void* d_out, int out_size, void* d_ws, size_t ws_size,
                              hipStream_t stream)
{
  const int*   paths_mm = (const int*)d_in[0];
  const int*   paths_dd = (const int*)d_in[1];
  const int*   paths_md = (const int*)d_in[2];
  const float* miRNA    = (const float*)d_in[3];
  const float* disease  = (const float*)d_in[4];
  const int*   samples  = (const int*)d_in[5];
  const float* Wm  = (const float*)d_in[6];
  const float* Wd  = (const float*)d_in[7];
  const float* pw1 = (const float*)d_in[8];
  const float* pw2 = (const float*)d_in[9];
  const float* fcW = (const float*)d_in[10];
  const float* W0  = (const float*)d_in[11];
  const float* b0  = (const float*)d_in[12];
  const float* W1  = (const float*)d_in[13];
  const float* b1  = (const float*)d_in[14];
  const float* W2  = (const float*)d_in[15];
  const float* b2  = (const float*)d_in[16];

  const int D  = 128;
  const int Nm = in_sizes[6] / D;
  const int Nd = in_sizes[7] / D;
  const int Nt = Nm + Nd;
  const int S  = in_sizes[5] / 2;
  const int layers = in_sizes[10] / (D * D);
  const int L1 = in_sizes[8] / (layers * D);
  const int L2 = in_sizes[9] / (layers * D);
  const int P  = in_sizes[0] / (Nm * L1);
  const int E  = 4 * D;
  const int K0 = in_sizes[12];
  const int H1 = in_sizes[14];
  const int Kpm = cdiv(Nm, 64) * 64;   // 8000
  const int Kpd = cdiv(Nd, 64) * 64;   // 6016
  const size_t NtD = (size_t)Nt * D;

  float* out = (float*)d_out;
  float* ws  = (float*)d_ws;
  size_t off = 0;
  float* init   = ws + off; off += NtD;                              // f32 summed init
  __hip_bfloat16* stateA = (__hip_bfloat16*)(ws + off); off += NtD;  // 2*NtD bf16
  __hip_bfloat16* stateB = (__hip_bfloat16*)(ws + off); off += NtD;  // 2*NtD bf16
  float* w01    = ws + off; off += (size_t)E * H1;
  float* b01    = ws + off; off += H1;
  float* w512   = ws + off; off += E;
  float* csc    = ws + off; off += 1;
  float* uv     = ws + off; off += Nt;
  __hip_bfloat16* WtTm = (__hip_bfloat16*)(ws + off); off += (size_t)D * Kpm / 2;
  __hip_bfloat16* WtTd = (__hip_bfloat16*)(ws + off); off += (size_t)D * Kpd / 2;
  float* pextra = ws + off;
  (void)n_in; (void)out_size;

  // 1. tile-major bf16 weight transposes
  make_wtT<<<Kpm / 32, 256, 0, stream>>>(Wm, WtTm, Nm);
  make_wtT<<<Kpd / 32, 256, 0, stream>>>(Wd, WtTd, Nd);

  // 2. MLP collapse
  collapse1<<<E + 1, 64, 0, stream>>>(W0, b0, W1, b1, w01, b01, E, K0, H1);
  collapse2<<<cdiv(E + 1, 256), 256, 0, stream>>>(w01, b01, W2, b2, w512, csc, E, H1);

  // 3. init GEMMs: BM=256 / BK=64 (halved W traffic), split-K sized to workspace
  {
    int nbm = cdiv(Nm, 256), nbd = cdiv(Nd, 256);
    int n4 = (int)(NtD / 4);
    P12 parr;
    parr.p[0] = init;
    parr.p[1] = (float*)stateB;      // free until layer 0 (combineN runs before layers)
    for (int j = 0; j < 10; ++j) parr.p[2 + j] = pextra + (size_t)j * NtD;
    if ((off + 7 * NtD) * 4 <= ws_size) {
      init_mfma6<9><<<(nbm + nbd) * 9, 512, 0, stream>>>(
          miRNA, WtTm, Nm, nbm, Kpm, disease, WtTd, Nd, Kpd, parr);
      combineN<9><<<cdiv(n4, 256), 256, 0, stream>>>(parr, (float4v*)init, stateA, n4, (int)NtD);
    } else if ((off + 4 * NtD) * 4 <= ws_size) {
      init_mfma6<6><<<(nbm + nbd) * 6, 512, 0, stream>>>(
          miRNA, WtTm, Nm, nbm, Kpm, disease, WtTd, Nd, Kpd, parr);
      combineN<6><<<cdiv(n4, 256), 256, 0, stream>>>(parr, (float4v*)init, stateA, n4, (int)NtD);
    } else {
      init_mfma6<3><<<(nbm + nbd) * 3, 512, 0, stream>>>(
          miRNA, WtTm, Nm, nbm, Kpm, disease, WtTd, Nd, Kpd, parr);
      combineN<3><<<cdiv(n4, 256), 256, 0, stream>>>(parr, (float4v*)init, stateA, n4, (int)NtD);
    }
  }

  // 4. path layers: fused gather+fc with ping-pong state
  const bool fuse_ok = (L1 == 4 && L2 == 6 && P == 8 &&
                        Nm % 16 == 0 && Nd % 16 == 0 && Nt % 16 == 0);
  __hip_bfloat16* cur = stateA;
  __hip_bfloat16* nxt = stateB;
  for (int l = 0; l < layers; ++l) {
    const float* pw1l = pw1 + (size_t)l * L1 * D;
    const float* pw2l = pw2 + (size_t)l * L2 * D;
    const float* fcWl = fcW + (size_t)l * D * D;
    if (fuse_ok) {
      int nbm16 = Nm / 16, nbd16 = Nd / 16, nbt16 = Nt / 16;
      layer_fused<4, 6, 8><<<nbm16 + nbd16 + nbt16, 256, 0, stream>>>(
          cur, paths_mm, paths_dd, paths_md, pw1l, pw2l, fcWl, init, nxt,
          Nm, Nd, nbm16, nbd16);
    } else {
      float* bufR = pextra;
      gather_einsum_rt<<<cdiv(Nm, 2), 256, 0, stream>>>(cur, paths_mm, pw1l, bufR, Nm, P, L1);
      gather_einsum_rt<<<cdiv(Nd, 2), 256, 0, stream>>>(cur + (size_t)Nm * D, paths_dd, pw1l,
                                                        bufR + (size_t)Nm * D, Nd, P, L1);
      gather_einsum_rt<<<cdiv(Nt, 2), 256, 0, stream>>>(cur + NtD, paths_md, pw2l,
                                                        bufR + NtD, Nt, P, L2);
      fc_all<8><<<cdiv(2 * Nt, 16), 256, 0, stream>>>(
          bufR, fcWl, init, nxt, 2 * Nt, Nt);
    }
    __hip_bfloat16* tmp = cur; cur = nxt; nxt = tmp;
  }

  // 5. per-node partial dots + scoring
  node_partial<<<cdiv(Nt * 64, 256), 256, 0, stream>>>(
      cur, cur + (size_t)Nm * D, cur + NtD, w512, uv, Nm, Nt);
  score_kernel<<<cdiv(S, 256), 256, 0, stream>>>(samples, uv, uv + Nm, csc, out, S);
}